// Round 9
// baseline (115.875 us; speedup 1.0000x reference)
//
#include <hip/hip_runtime.h>

// B=2, HEADS=8, T=8, QH=QW=16, D=64; rows = 32768, K = 2048.
// out[row, k] = scores[row, k] + dotH(qh,kh) + dotW(qw,kw) + dotT(t,kt)
// k = kt*256 + kh*16 + kw; row = (b*H+n)*2048 + t*256 + qh*16 + qw.
//
// v9: two-phase. Kernel A computes all 32768x40 bias dots (v8's coalesced
// butterfly prelude) into d_ws as [row][48] floats (192B rows, 16B-aligned
// W block). Kernel B is a near-pure copy stream: ~10 L1-hit bias loads from
// one 192B ws row, then 8 nt loads + 8 adds + 8 nt stores per wave-row.

#define ROWS 4

typedef float v4f __attribute__((ext_vector_type(4)));

__global__ __launch_bounds__(256) void relpos_bias_kernel(
    const float* __restrict__ query,   // [32768, 64]
    const float* __restrict__ hemb,    // [31, 64]
    const float* __restrict__ wemb,    // [31, 64]
    const float* __restrict__ temb,    // [15, 64]
    float* __restrict__ bias_ws)       // [32768, 48]
{
    __shared__ __align__(16) float bias_all[ROWS][48];

    const int tid  = threadIdx.x;
    const int wv   = tid >> 6;
    const int lane = tid & 63;

    const int grow = blockIdx.x * ROWS + wv;
    const int row  = grow & 2047;
    const int tt   = row >> 8;
    const int qh   = (row >> 4) & 15;
    const int qw   = row & 15;

    const int g = lane >> 4;   // group 0..3
    const int i = lane & 15;   // position within group

    const v4f q4 = ((const v4f*)(query + (size_t)grow * 64))[i];

    #pragma unroll
    for (int j = 0; j < 10; ++j) {
        const int d = g * 10 + j;          // dot index 0..39
        const float* erow;
        if (d < 16)      erow = hemb + (qh - d + 15) * 64;
        else if (d < 32) erow = wemb + (qw - (d - 16) + 15) * 64;
        else             erow = temb + (tt - (d - 32) + 7) * 64;
        const v4f e4 = ((const v4f*)erow)[i];
        const v4f p4 = q4 * e4;
        float p = (p4.x + p4.y) + (p4.z + p4.w);
        p += __shfl_xor(p, 1, 64);
        p += __shfl_xor(p, 2, 64);
        p += __shfl_xor(p, 4, 64);
        p += __shfl_xor(p, 8, 64);
        if (i == 0) bias_all[wv][d] = p;
    }
    // Own-wave LDS write->read: no barrier needed.
    if (lane < 40)
        bias_ws[(size_t)grow * 48 + lane] = bias_all[wv][lane];
}

__global__ __launch_bounds__(256, 8) void relpos_stream_kernel(
    const float* __restrict__ scores,  // [32768, 2048]
    const float* __restrict__ bias_ws, // [32768, 48]
    float* __restrict__ out)           // [32768, 2048]
{
    const int tid  = threadIdx.x;
    const int wv   = tid >> 6;
    const int lane = tid & 63;
    const int grow = blockIdx.x * ROWS + wv;

    // element = i*256 + lane*4 + c  =>  kt=i, kh=lane>>2, kw quad = lane&3
    const float* bw = bias_ws + (size_t)grow * 48;
    const float h  = bw[lane >> 2];
    const v4f  w4  = *(const v4f*)(bw + 16 + (lane & 3) * 4);
    const v4f  hw4 = w4 + h;
    float tv[8];
    #pragma unroll
    for (int k = 0; k < 8; ++k) tv[k] = bw[32 + k];

    const v4f* s4p = (const v4f*)scores + (size_t)grow * 512 + lane;
    v4f*       o4p = (v4f*)out          + (size_t)grow * 512 + lane;

    v4f s[8];
    #pragma unroll
    for (int k = 0; k < 8; ++k)
        s[k] = __builtin_nontemporal_load(&s4p[k * 64]);
    #pragma unroll
    for (int k = 0; k < 8; ++k) {
        v4f o = s[k] + hw4 + tv[k];
        __builtin_nontemporal_store(o, &o4p[k * 64]);
    }
}

extern "C" void kernel_launch(void* const* d_in, const int* in_sizes, int n_in,
                              void* d_out, int out_size, void* d_ws, size_t ws_size,
                              hipStream_t stream) {
    const float* query  = (const float*)d_in[0];
    const float* scores = (const float*)d_in[1];
    const float* hemb   = (const float*)d_in[2];
    const float* wemb   = (const float*)d_in[3];
    const float* temb   = (const float*)d_in[4];
    float* out = (float*)d_out;
    float* bias_ws = (float*)d_ws;     // needs 32768*48*4 = 6.3 MB

    relpos_bias_kernel<<<32768 / ROWS, 256, 0, stream>>>(
        query, hemb, wemb, temb, bias_ws);
    relpos_stream_kernel<<<32768 / ROWS, 256, 0, stream>>>(
        scores, bias_ws, out);
}

// Round 10
// 94.756 us; speedup vs baseline: 1.2229x; 1.2229x over previous
//
#include <hip/hip_runtime.h>

// B=2, HEADS=8, T=8, QH=QW=16, D=64; rows = 32768, K = 2048.
// out[row, k] = scores[row, k] + dotH(qh,kh) + dotW(qw,kw) + dotT(t,kt)
// k = kt*256 + kh*16 + kw; row = (b*H+n)*2048 + t*256 + qh*16 + qw.
//
// v10: v8 (one wave/row, coalesced butterfly prelude, nt load + nt store,
// reg-hoisted biases, no barrier) with the 8 stream loads issued FIRST,
// pinned by sched_barrier(0), so each wave's long-latency HBM requests are
// in flight while the prelude computes.

#define ROWS 4

typedef float v4f __attribute__((ext_vector_type(4)));

__global__ __launch_bounds__(256, 8) void relpos_fused_v10(
    const float* __restrict__ query,   // [32768, 64]
    const float* __restrict__ scores,  // [32768, 2048]
    const float* __restrict__ hemb,    // [31, 64]
    const float* __restrict__ wemb,    // [31, 64]
    const float* __restrict__ temb,    // [15, 64]
    float* __restrict__ out)           // [32768, 2048]
{
    __shared__ __align__(16) float bias_all[ROWS][48];

    const int tid  = threadIdx.x;
    const int wv   = tid >> 6;             // wave id = local row
    const int lane = tid & 63;

    const int grow = blockIdx.x * ROWS + wv;  // global row [0, 32768)
    const int row  = grow & 2047;             // within (b,n)
    const int tt   = row >> 8;
    const int qh   = (row >> 4) & 15;
    const int qw   = row & 15;

    // --- Issue the 8 stream loads FIRST; pin them ahead of the prelude ---
    const v4f* s4p = (const v4f*)scores + (size_t)grow * 512 + lane;
    v4f*       o4p = (v4f*)out          + (size_t)grow * 512 + lane;
    v4f s[8];
    #pragma unroll
    for (int k = 0; k < 8; ++k)
        s[k] = __builtin_nontemporal_load(&s4p[k * 64]);
    __builtin_amdgcn_sched_barrier(0);   // don't sink these below the prelude

    // --- Coalesced prelude: 4 groups x 10 dots, butterfly over 16 lanes ---
    const int g = lane >> 4;   // group 0..3
    const int i = lane & 15;   // position within group

    const v4f q4 = ((const v4f*)(query + (size_t)grow * 64))[i];

    #pragma unroll
    for (int j = 0; j < 10; ++j) {
        const int d = g * 10 + j;          // dot index 0..39
        const float* erow;
        if (d < 16)      erow = hemb + (qh - d + 15) * 64;
        else if (d < 32) erow = wemb + (qw - (d - 16) + 15) * 64;
        else             erow = temb + (tt - (d - 32) + 7) * 64;
        const v4f e4 = ((const v4f*)erow)[i];
        const v4f p4 = q4 * e4;
        float p = (p4.x + p4.y) + (p4.z + p4.w);
        p += __shfl_xor(p, 1, 64);
        p += __shfl_xor(p, 2, 64);
        p += __shfl_xor(p, 4, 64);
        p += __shfl_xor(p, 8, 64);
        if (i == 0) bias_all[wv][d] = p;
    }
    // Own-wave LDS write->read: no barrier needed.

    // element = i*256 + lane*4 + c  =>  kt=i, kh=lane>>2, kw quad = lane&3
    const float h  = bias_all[wv][lane >> 2];
    const v4f  w4 = ((const v4f*)(&bias_all[wv][16]))[lane & 3];
    const v4f  hw4 = w4 + h;
    float tv[8];
    #pragma unroll
    for (int k = 0; k < 8; ++k) tv[k] = bias_all[wv][32 + k];

    // --- Add + nt store ---
    #pragma unroll
    for (int k = 0; k < 8; ++k) {
        v4f o = s[k] + hw4 + tv[k];
        __builtin_nontemporal_store(o, &o4p[k * 64]);
    }
}

extern "C" void kernel_launch(void* const* d_in, const int* in_sizes, int n_in,
                              void* d_out, int out_size, void* d_ws, size_t ws_size,
                              hipStream_t stream) {
    const float* query  = (const float*)d_in[0];
    const float* scores = (const float*)d_in[1];
    const float* hemb   = (const float*)d_in[2];
    const float* wemb   = (const float*)d_in[3];
    const float* temb   = (const float*)d_in[4];
    float* out = (float*)d_out;

    relpos_fused_v10<<<32768 / ROWS, 256, 0, stream>>>(
        query, scores, hemb, wemb, temb, out);
}